// Round 11
// baseline (529.653 us; speedup 1.0000x reference)
//
#include <hip/hip_runtime.h>

#define D 64
#define H 64
#define EFD 16
#define MS 68    // LDS tile row stride (floats) for pre_kernel
#define TE 128   // edges per tile
#define TN 128   // nodes per block (pre_kernel)
#define DPB4 32  // dsts per block (fused kernel)

typedef __attribute__((ext_vector_type(8))) short bf16x8;
typedef __attribute__((ext_vector_type(4))) float f32x4;

__device__ __forceinline__ float silu(float x) {
    return x / (1.0f + __expf(-x));
}

__device__ __forceinline__ short f2bf(float x) {   // RNE fp32->bf16
    union { float f; unsigned u; } c; c.f = x;
    unsigned r = c.u + 0x7fffu + ((c.u >> 16) & 1u);
    return (short)(r >> 16);
}

#define GEMM_STEP(acc_, a_, bf_) do { \
    const float* bp_ = (const float*)(bf_); \
    acc_[0] += (a_).x*bp_[0] + (a_).y*bp_[4] + (a_).z*bp_[8]  + (a_).w*bp_[12]; \
    acc_[1] += (a_).x*bp_[1] + (a_).y*bp_[5] + (a_).z*bp_[9]  + (a_).w*bp_[13]; \
    acc_[2] += (a_).x*bp_[2] + (a_).y*bp_[6] + (a_).z*bp_[10] + (a_).w*bp_[14]; \
    acc_[3] += (a_).x*bp_[3] + (a_).y*bp_[7] + (a_).z*bp_[11] + (a_).w*bp_[15]; \
} while (0)

#define PGEMM64(acc_, Wp_, wrow0_, eg_, hg_, smem_) do { \
    for (int k4 = 0; k4 < 16; k4++) { \
        float4 bf_[4]; \
        _Pragma("unroll") \
        for (int kk = 0; kk < 4; kk++) \
            bf_[kk] = *(const float4*)&(Wp_)[(size_t)((wrow0_) + 4*k4 + kk) * H + 4*(hg_)]; \
        _Pragma("unroll") \
        for (int i = 0; i < 8; i++) { \
            float4 a_ = *(const float4*)&(smem_)[(8*(eg_) + i) * MS + 4*k4]; \
            GEMM_STEP(acc_[i], a_, bf_); \
        } \
    } \
} while (0)

// ---------------- histogram ----------------

__global__ __launch_bounds__(256) void hist_kernel(
    const int* __restrict__ dst, int* __restrict__ deg, int E)
{
    int e = blockIdx.x * 256 + threadIdx.x;
    if (e < E) atomicAdd(&deg[dst[e]], 1);
}

// ---------------- 3-phase multi-block exclusive scan ----------------

__global__ __launch_bounds__(256) void scanA_kernel(
    const int* __restrict__ deg, int* __restrict__ part, int N)
{
    __shared__ int tmp[256];
    const int tid = threadIdx.x;
    int idx = blockIdx.x * 256 + tid;
    tmp[tid] = (idx < N) ? deg[idx] : 0;
    __syncthreads();
    for (int off = 128; off > 0; off >>= 1) {
        if (tid < off) tmp[tid] += tmp[tid + off];
        __syncthreads();
    }
    if (tid == 0) part[blockIdx.x] = tmp[0];
}

__global__ __launch_bounds__(256, 1) void scanB_kernel(
    int* __restrict__ part, int nparts)
{
    __shared__ int tmp[256];
    __shared__ int carry_s;
    const int tid = threadIdx.x;
    if (tid == 0) carry_s = 0;
    __syncthreads();
    for (int base = 0; base < nparts; base += 256) {
        int idx = base + tid;
        int v = (idx < nparts) ? part[idx] : 0;
        tmp[tid] = v;
        __syncthreads();
        #pragma unroll
        for (int off = 1; off < 256; off <<= 1) {
            int t = (tid >= off) ? tmp[tid - off] : 0;
            __syncthreads();
            tmp[tid] += t;
            __syncthreads();
        }
        int incl = tmp[tid];
        int tot = tmp[255];
        if (idx < nparts) part[idx] = carry_s + incl - v;  // exclusive
        __syncthreads();
        if (tid == 0) carry_s += tot;
        __syncthreads();
    }
}

__global__ __launch_bounds__(256) void scanC_kernel(
    const int* __restrict__ deg, const int* __restrict__ part,
    int* __restrict__ cursor, int N)
{
    __shared__ int tmp[256];
    const int tid = threadIdx.x;
    int idx = blockIdx.x * 256 + tid;
    int v = (idx < N) ? deg[idx] : 0;
    tmp[tid] = v;
    __syncthreads();
    #pragma unroll
    for (int off = 1; off < 256; off <<= 1) {
        int t = (tid >= off) ? tmp[tid - off] : 0;
        __syncthreads();
        tmp[tid] += t;
        __syncthreads();
    }
    if (idx < N) cursor[idx] = part[blockIdx.x] + tmp[tid] - v;
}

// ---------------- build: permutation + gathered src/dst, sorted by dst ----------------

__global__ __launch_bounds__(256) void build2_kernel(
    const int* __restrict__ dst, const int* __restrict__ src,
    int* __restrict__ cursor,
    int* __restrict__ eidx, int* __restrict__ srcs, int* __restrict__ dsts,
    int E)
{
    int e = blockIdx.x * 256 + threadIdx.x;
    if (e < E) {
        int d2 = dst[e];
        int pos = atomicAdd(&cursor[d2], 1);
        eidx[pos] = e;
        srcs[pos] = src[e];
        dsts[pos] = d2;
    }
}

// ---------------- Pa/Pb precompute ----------------
// Pa = node_feat @ W_e1[0:64] + b_e1 ; Pb = node_feat @ W_e1[64:128]

__global__ __launch_bounds__(256, 4) void pre_kernel(
    const float* __restrict__ node_feat,
    const float* __restrict__ W_e1, const float* __restrict__ b_e1,
    float* __restrict__ Pa, float* __restrict__ Pb, int N)
{
    __shared__ float smem[TN * MS];
    const int tid = threadIdx.x;
    const int nbase = blockIdx.x * TN;
    const int ng = tid >> 4, hg = tid & 15, k = tid & 63, no = tid >> 6;

    #pragma unroll
    for (int t = 0; t < 32; t++) {
        int gn = nbase + no + 4*t;
        int cg = (gn < N) ? gn : (N - 1);
        smem[(no + 4*t) * MS + k] = node_feat[(size_t)cg * D + k];
    }
    __syncthreads();

    float accA[8][4], accB[8][4];
    {
        float4 b0 = *(const float4*)&b_e1[4*hg];
        #pragma unroll
        for (int i = 0; i < 8; i++) {
            accA[i][0]=b0.x; accA[i][1]=b0.y; accA[i][2]=b0.z; accA[i][3]=b0.w;
            accB[i][0]=0.f;  accB[i][1]=0.f;  accB[i][2]=0.f;  accB[i][3]=0.f;
        }
    }
    PGEMM64(accA, W_e1, 0,  ng, hg, smem);
    PGEMM64(accB, W_e1, 64, ng, hg, smem);

    #pragma unroll
    for (int i = 0; i < 8; i++) {
        int gn = nbase + 8*ng + i;
        if (gn < N) {
            float4 a; a.x=accA[i][0]; a.y=accA[i][1]; a.z=accA[i][2]; a.w=accA[i][3];
            float4 b; b.x=accB[i][0]; b.y=accB[i][1]; b.z=accB[i][2]; b.w=accB[i][3];
            *(float4*)&Pa[(size_t)gn * H + 4*hg] = a;
            *(float4*)&Pb[(size_t)gn * H + 4*hg] = b;
        }
    }
}

// ---------------- fused edge+node kernel ----------------
// Per block: 32 dsts. Edge loop (barrier-free, wave-private m rows, MFMA MLP2)
// accumulates h_neigh rows in LDS hacc; then node MLP (bf16 MFMA) runs in-block
// on z = [node_feat | hacc] and stores the final output rows directly.

__global__ __launch_bounds__(256, 3) void fused_kernel(
    const float* __restrict__ Pa, const float* __restrict__ Pb,
    const int* __restrict__ srcs, const int* __restrict__ dsts,
    const int* __restrict__ eidx,
    const float* __restrict__ edge_feat, const float* __restrict__ coord,
    const int* __restrict__ cursor_end, const int* __restrict__ deg,
    const float* __restrict__ W_e1,
    const float* __restrict__ W_e2, const float* __restrict__ b_e2,
    const float* __restrict__ node_feat,
    const float* __restrict__ W_n1, const float* __restrict__ b_n1,
    const float* __restrict__ W_n2, const float* __restrict__ b_n2,
    float* __restrict__ out, int N)
{
    __shared__ alignas(16) short mt[TE * H];   // bf16 m tile (16 KB), reused for y1
    __shared__ float hacc[DPB4 * H];           // per-dst accumulator (8 KB)

    const int tid = threadIdx.x;
    const int lane = tid & 63;
    const int wv = tid >> 6;       // wave 0..3
    const int lg = lane >> 4;      // k-group 0..3
    const int lc = lane & 15;      // row/col-in-frag
    const int eg = tid >> 4;       // phase-1 row group
    const int hg = tid & 15;       // phase-1 col group

    const int dst0 = blockIdx.x * DPB4;
    const int dlast = min(dst0 + DPB4, N) - 1;
    const int rs = cursor_end[dst0] - deg[dst0];
    const int re = cursor_end[dlast];

    for (int i = tid; i < DPB4 * H; i += 256) hacc[i] = 0.f;

    // W_e2 bf16 B-frags (once per block). B[k][col]: k=lg*8+t+32ks, col=16nf+lc
    bf16x8 bfr[2][4];
    #pragma unroll
    for (int ks = 0; ks < 2; ks++)
        #pragma unroll
        for (int nf = 0; nf < 4; nf++) {
            bf16x8 v;
            #pragma unroll
            for (int t = 0; t < 8; t++)
                v[t] = f2bf(W_e2[(size_t)(lg*8 + t + 32*ks) * H + 16*nf + lc]);
            bfr[ks][nf] = v;
        }
    float bias[4];
    #pragma unroll
    for (int nf = 0; nf < 4; nf++) bias[nf] = b_e2[16*nf + lc];

    __syncthreads();   // hacc init visible before any atomics

    for (int base = rs; base < re; base += TE) {
        // ---- row indices for this thread's 8 edge rows ----
        int sS[8], sD[8], sE[8];
        #pragma unroll
        for (int i = 0; i < 8; i++) {
            int p = base + 8*eg + i;
            int pp = (p < re) ? p : (re - 1);
            sS[i] = srcs[pp]; sD[i] = dsts[pp]; sE[i] = eidx[pp];
        }

        // ---- phase 1 (fp32): acc = Pa[src]+Pb[dst] + [radial|ef]@W1c ----
        float a1[8][4];
        #pragma unroll
        for (int i = 0; i < 8; i++) {
            float4 pa = *(const float4*)&Pa[(size_t)sS[i] * H + 4*hg];
            float4 pb = *(const float4*)&Pb[(size_t)sD[i] * H + 4*hg];
            a1[i][0] = pa.x + pb.x; a1[i][1] = pa.y + pb.y;
            a1[i][2] = pa.z + pb.z; a1[i][3] = pa.w + pb.w;
        }
        float rad[8];
        #pragma unroll
        for (int i = 0; i < 8; i++) {
            const float* cs = &coord[(size_t)sS[i] * 3];
            const float* cd = &coord[(size_t)sD[i] * 3];
            float dx = cs[0]-cd[0], dy = cs[1]-cd[1], dz = cs[2]-cd[2];
            rad[i] = dx*dx + dy*dy + dz*dz;
        }
        for (int k4 = 0; k4 < 4; k4++) {
            float4 bf[4];
            #pragma unroll
            for (int kk = 0; kk < 4; kk++)
                bf[kk] = *(const float4*)&W_e1[(size_t)(129 + 4*k4 + kk) * H + 4*hg];
            #pragma unroll
            for (int i = 0; i < 8; i++) {
                float4 a = *(const float4*)&edge_feat[(size_t)sE[i] * EFD + 4*k4];
                GEMM_STEP(a1[i], a, bf);
            }
        }
        {
            float4 b = *(const float4*)&W_e1[(size_t)128 * H + 4*hg];
            #pragma unroll
            for (int i = 0; i < 8; i++) {
                a1[i][0] += rad[i]*b.x; a1[i][1] += rad[i]*b.y;
                a1[i][2] += rad[i]*b.z; a1[i][3] += rad[i]*b.w;
            }
        }

        // ---- m = silu -> bf16 -> swizzled LDS (wave-private rows) ----
        #pragma unroll
        for (int i = 0; i < 8; i++) {
            short4 mv;
            mv.x = f2bf(silu(a1[i][0])); mv.y = f2bf(silu(a1[i][1]));
            mv.z = f2bf(silu(a1[i][2])); mv.w = f2bf(silu(a1[i][3]));
            int row = 8*eg + i;                      // row&7 == i
            int sidx = (row * H + 4*hg) ^ (i << 3);
            *(short4*)&mt[sidx] = mv;
        }
        asm volatile("s_waitcnt lgkmcnt(0)" ::: "memory");

        // ---- MLP2 via MFMA: wave wv owns rows 32wv..32wv+31 ----
        bf16x8 afr[2][2];
        #pragma unroll
        for (int mf = 0; mf < 2; mf++)
            #pragma unroll
            for (int ks = 0; ks < 2; ks++) {
                int row = 32*wv + 16*mf + lc;
                int sidx = (row * H + lg*8 + 32*ks) ^ ((lc & 7) << 3);
                afr[mf][ks] = *(const bf16x8*)&mt[sidx];
            }
        f32x4 c2[2][4];
        #pragma unroll
        for (int mf = 0; mf < 2; mf++)
            #pragma unroll
            for (int nf = 0; nf < 4; nf++) {
                f32x4 ci = {bias[nf], bias[nf], bias[nf], bias[nf]};
                c2[mf][nf] = ci;
            }
        #pragma unroll
        for (int ks = 0; ks < 2; ks++)
            #pragma unroll
            for (int mf = 0; mf < 2; mf++)
                #pragma unroll
                for (int nf = 0; nf < 4; nf++)
                    c2[mf][nf] = __builtin_amdgcn_mfma_f32_16x16x32_bf16(
                        afr[mf][ks], bfr[ks][nf], c2[mf][nf], 0, 0, 0);

        // ---- epilogue: silu + run-combine + LDS atomics ----
        #pragma unroll
        for (int mf = 0; mf < 2; mf++) {
            int rb = 32*wv + 16*mf + 4*lg;
            int cur = -1;
            float s0 = 0.f, s1 = 0.f, s2 = 0.f, s3 = 0.f;
            #pragma unroll
            for (int reg = 0; reg < 4; reg++) {
                int p = base + rb + reg;
                if (p < re) {
                    int dl = dsts[p] - dst0;
                    float v0 = silu(c2[mf][0][reg]);
                    float v1 = silu(c2[mf][1][reg]);
                    float v2 = silu(c2[mf][2][reg]);
                    float v3 = silu(c2[mf][3][reg]);
                    if (dl != cur) {
                        if (cur >= 0) {
                            atomicAdd(&hacc[cur*H + lc],      s0);
                            atomicAdd(&hacc[cur*H + 16 + lc], s1);
                            atomicAdd(&hacc[cur*H + 32 + lc], s2);
                            atomicAdd(&hacc[cur*H + 48 + lc], s3);
                        }
                        cur = dl; s0 = v0; s1 = v1; s2 = v2; s3 = v3;
                    } else { s0 += v0; s1 += v1; s2 += v2; s3 += v3; }
                }
            }
            if (cur >= 0) {
                atomicAdd(&hacc[cur*H + lc],      s0);
                atomicAdd(&hacc[cur*H + 16 + lc], s1);
                atomicAdd(&hacc[cur*H + 32 + lc], s2);
                atomicAdd(&hacc[cur*H + 48 + lc], s3);
            }
        }
    }

    __syncthreads();   // hacc final; mt free for reuse

    // ================= node MLP (bf16 MFMA), 32 rows =================
    // z = [node_feat(64) | hacc(64)], K=128. Wave wv owns output cols 16wv..16wv+15.

    // A-frags: row = 16mf+lc, k = lg*8 + t + 32ks
    bf16x8 an[2][4];
    #pragma unroll
    for (int mf = 0; mf < 2; mf++) {
        int row = 16*mf + lc;
        int gr = dst0 + row; if (gr >= N) gr = N - 1;
        #pragma unroll
        for (int ks = 0; ks < 4; ks++) {
            float4 u0, u1;
            if (ks < 2) {
                const float* q = &node_feat[(size_t)gr * D + lg*8 + 32*ks];
                u0 = *(const float4*)&q[0];
                u1 = *(const float4*)&q[4];
            } else {
                const float* q = &hacc[row * H + lg*8 + 32*(ks-2)];
                u0 = *(const float4*)&q[0];
                u1 = *(const float4*)&q[4];
            }
            bf16x8 v;
            v[0]=f2bf(u0.x); v[1]=f2bf(u0.y); v[2]=f2bf(u0.z); v[3]=f2bf(u0.w);
            v[4]=f2bf(u1.x); v[5]=f2bf(u1.y); v[6]=f2bf(u1.z); v[7]=f2bf(u1.w);
            an[mf][ks] = v;
        }
    }
    // B-frags: W_n1[k][16wv+lc]
    bf16x8 bn1[4];
    #pragma unroll
    for (int ks = 0; ks < 4; ks++) {
        bf16x8 v;
        #pragma unroll
        for (int t = 0; t < 8; t++)
            v[t] = f2bf(W_n1[(size_t)(lg*8 + t + 32*ks) * H + 16*wv + lc]);
        bn1[ks] = v;
    }
    float bb1 = b_n1[16*wv + lc];
    f32x4 c1[2];
    {
        f32x4 ci = {bb1, bb1, bb1, bb1};
        c1[0] = ci; c1[1] = ci;
    }
    #pragma unroll
    for (int ks = 0; ks < 4; ks++)
        #pragma unroll
        for (int mf = 0; mf < 2; mf++)
            c1[mf] = __builtin_amdgcn_mfma_f32_16x16x32_bf16(an[mf][ks], bn1[ks], c1[mf], 0, 0, 0);

    // y1 = silu(c1) -> mt (swizzled); D layout: row = 16mf+4lg+reg, col = 16wv+lc
    #pragma unroll
    for (int mf = 0; mf < 2; mf++)
        #pragma unroll
        for (int reg = 0; reg < 4; reg++) {
            int r = 16*mf + 4*lg + reg;
            int sidx = (r * H + 16*wv + lc) ^ ((r & 7) << 3);
            mt[sidx] = f2bf(silu(c1[mf][reg]));
        }
    __syncthreads();   // y1 visible across waves

    // MLP2: K=64 from y1
    bf16x8 a2[2][2];
    #pragma unroll
    for (int mf = 0; mf < 2; mf++)
        #pragma unroll
        for (int ks = 0; ks < 2; ks++) {
            int row = 16*mf + lc;
            int sidx = (row * H + lg*8 + 32*ks) ^ ((lc & 7) << 3);
            a2[mf][ks] = *(const bf16x8*)&mt[sidx];
        }
    bf16x8 bn2[2];
    #pragma unroll
    for (int ks = 0; ks < 2; ks++) {
        bf16x8 v;
        #pragma unroll
        for (int t = 0; t < 8; t++)
            v[t] = f2bf(W_n2[(size_t)(lg*8 + t + 32*ks) * H + 16*wv + lc]);
        bn2[ks] = v;
    }
    float bb2 = b_n2[16*wv + lc];
    f32x4 co[2];
    {
        f32x4 ci = {bb2, bb2, bb2, bb2};
        co[0] = ci; co[1] = ci;
    }
    #pragma unroll
    for (int ks = 0; ks < 2; ks++)
        #pragma unroll
        for (int mf = 0; mf < 2; mf++)
            co[mf] = __builtin_amdgcn_mfma_f32_16x16x32_bf16(a2[mf][ks], bn2[ks], co[mf], 0, 0, 0);

    #pragma unroll
    for (int mf = 0; mf < 2; mf++)
        #pragma unroll
        for (int reg = 0; reg < 4; reg++) {
            int r = 16*mf + 4*lg + reg;
            int gn = dst0 + r;
            if (gn < N)
                out[(size_t)gn * D + 16*wv + lc] = co[mf][reg];
        }
}

extern "C" void kernel_launch(void* const* d_in, const int* in_sizes, int n_in,
                              void* d_out, int out_size, void* d_ws, size_t ws_size,
                              hipStream_t stream)
{
    const float* node_feat = (const float*)d_in[0];
    const float* coord     = (const float*)d_in[1];
    const float* edge_feat = (const float*)d_in[2];
    const int*   src       = (const int*)d_in[3];
    const int*   dst       = (const int*)d_in[4];
    const float* W_e1 = (const float*)d_in[5];
    const float* b_e1 = (const float*)d_in[6];
    const float* W_e2 = (const float*)d_in[7];
    const float* b_e2 = (const float*)d_in[8];
    const float* W_n1 = (const float*)d_in[9];
    const float* b_n1 = (const float*)d_in[10];
    const float* W_n2 = (const float*)d_in[11];
    const float* b_n2 = (const float*)d_in[12];

    const int N = in_sizes[0] / D;
    const int E = in_sizes[3];
    const int NP = (N + 255) / 256;

    const size_t n_i  = (size_t)N * sizeof(int);
    const size_t e_i  = (size_t)E * sizeof(int);
    const size_t pt_b = 1024 * sizeof(int);
    const size_t p_b  = (size_t)N * H * sizeof(float);

    // layout: deg | cursor | part | eidx | srcs | dsts | Pa | Pb  (~36 MB)
    char* p = (char*)d_ws;
    int* deg    = (int*)p;   p += n_i;
    int* cursor = (int*)p;   p += n_i;
    int* part   = (int*)p;   p += pt_b;
    int* eidx   = (int*)p;   p += e_i;
    int* srcs   = (int*)p;   p += e_i;
    int* dsts   = (int*)p;   p += e_i;
    float* Pa   = (float*)p; p += p_b;
    float* Pb   = (float*)p;

    hipMemsetAsync(deg, 0, n_i, stream);
    hist_kernel<<<(E + 255) / 256, 256, 0, stream>>>(dst, deg, E);
    scanA_kernel<<<NP, 256, 0, stream>>>(deg, part, N);
    scanB_kernel<<<1, 256, 0, stream>>>(part, NP);
    scanC_kernel<<<NP, 256, 0, stream>>>(deg, part, cursor, N);
    build2_kernel<<<(E + 255) / 256, 256, 0, stream>>>(dst, src, cursor,
                                                       eidx, srcs, dsts, E);
    pre_kernel<<<(N + TN - 1) / TN, 256, 0, stream>>>(node_feat, W_e1, b_e1,
                                                      Pa, Pb, N);
    const int dblocks = (N + DPB4 - 1) / DPB4;
    fused_kernel<<<dblocks, 256, 0, stream>>>(Pa, Pb, srcs, dsts, eidx,
                                              edge_feat, coord, cursor, deg,
                                              W_e1, W_e2, b_e2,
                                              node_feat, W_n1, b_n1, W_n2, b_n2,
                                              (float*)d_out, N);
}